// Round 8
// baseline (311.633 us; speedup 1.0000x reference)
//
#include <hip/hip_runtime.h>
#include <math.h>

#define D 64
#define K 512
#define BLOCK 256
#define NSLICES 8
#define KSLICE 64               // codes per block (grid.y slice)
#define KG 4                    // waves per block = k-groups
#define KT 16                   // codes per thread (KSLICE/KG)
#define RT 4                    // rows per thread
#define ROWS_PB 256             // rows per block = 64 lanes * RT

// Bit-exact emulation of the harness's numpy fp32 reference (validated
// rounds 3-7 at absmax 0.0):
//   dist[i,k] = fp32( fp32(sx[i] + se[k]) - 2*dot[i,k] )   (2*dot exact)
// sx/se = numpy pairwise 8-accumulator sums of squares (contraction OFF),
// dot = single-accumulator fmaf chain, j = 0..63 strictly ascending.
// argmin strict-<, k ascending -> first occurrence.
//
// R8 design: 2-D register tile. Thread owns Rt=4 rows x Kt=16 codes
// (acc[4][16]); wave w = k-group (e LDS address wave-uniform -> free
// broadcast, m136); x read once per (row,j4) via immediate-offset global
// loads (L1/L2). Per j4: 4 x-loads + 16 ds_read_b128 + 256 FMAs -> ~88%
// FMA density vs R4's ~40% (spill) / R6's ~33%. No semaphore (R7 41ms
// pathology); validated stash+merge+finalize pipeline.

__device__ __forceinline__ float np_sumsq64_g(const float* v) {
#pragma clang fp contract(off)
    float r[8];
    {
        float4 a = *(const float4*)(v + 0);
        float4 b = *(const float4*)(v + 4);
        r[0] = a.x * a.x; r[1] = a.y * a.y; r[2] = a.z * a.z; r[3] = a.w * a.w;
        r[4] = b.x * b.x; r[5] = b.y * b.y; r[6] = b.z * b.z; r[7] = b.w * b.w;
    }
#pragma unroll
    for (int i = 1; i < 8; ++i) {
        float4 a = *(const float4*)(v + i * 8 + 0);
        float4 b = *(const float4*)(v + i * 8 + 4);
        r[0] = r[0] + a.x * a.x; r[1] = r[1] + a.y * a.y;
        r[2] = r[2] + a.z * a.z; r[3] = r[3] + a.w * a.w;
        r[4] = r[4] + b.x * b.x; r[5] = r[5] + b.y * b.y;
        r[6] = r[6] + b.z * b.z; r[7] = r[7] + b.w * b.w;
    }
    return ((r[0] + r[1]) + (r[2] + r[3])) + ((r[4] + r[5]) + (r[6] + r[7]));
}

// Pass 1: block = 256 rows x 64-code slice. Wave kg scans codes
// [kbase+kg*16, +16) for rows (lane + 64*m). Stash (d,k) float2 per
// (row, slice) at q_out[row*64 + slice*2].
__global__ __launch_bounds__(BLOCK) void vq_scan(
    const float* __restrict__ x, const float* __restrict__ emb,
    float* __restrict__ stash, int N)
{
    __shared__ float4 e_s[KSLICE * 16];     // [code][j4], 16 KB
    __shared__ float se_s[KSLICE];
    __shared__ float2 part[KG][ROWS_PB];    // 8 KB

    const int tid = threadIdx.x;
    const int kg = tid >> 6;                // wave id -> e addr wave-uniform
    const int r  = tid & 63;
    const int kbase = blockIdx.y * KSLICE;

    // stage e slice (1024 float4, coalesced, 4/thread)
    const float4* esrc = (const float4*)(emb + (size_t)kbase * D);
#pragma unroll
    for (int i = 0; i < (KSLICE * 16) / BLOCK; ++i)
        e_s[tid + i * BLOCK] = esrc[tid + i * BLOCK];
    if (tid < KSLICE)
        se_s[tid] = np_sumsq64_g(emb + (size_t)(kbase + tid) * D);
    __syncthreads();

    const int rowbase = blockIdx.x * ROWS_PB;
    const float4* xp[RT];
    float sx[RT];
    bool vr[RT];
#pragma unroll
    for (int m = 0; m < RT; ++m) {
        int row = rowbase + r + 64 * m;
        vr[m] = row < N;
        int rowc = vr[m] ? row : 0;          // clamp loads, predicate stores
        xp[m] = (const float4*)(x + (size_t)rowc * D);
        sx[m] = np_sumsq64_g(x + (size_t)rowc * D);
    }

    float acc[RT][KT];
#pragma unroll
    for (int m = 0; m < RT; ++m)
#pragma unroll
        for (int kt = 0; kt < KT; ++kt) acc[m][kt] = 0.f;

#pragma unroll 1
    for (int j4 = 0; j4 < 16; ++j4) {
        float4 xv[RT];
#pragma unroll
        for (int m = 0; m < RT; ++m) xv[m] = xp[m][j4];
#pragma unroll
        for (int kt = 0; kt < KT; ++kt) {
            float4 e = e_s[(kg * KT + kt) * 16 + j4];   // uniform broadcast
#pragma unroll
            for (int m = 0; m < RT; ++m) {
                // j-ascending sequential chain per (row,code) — ref order
                float a = acc[m][kt];
                a = fmaf(xv[m].x, e.x, a);
                a = fmaf(xv[m].y, e.y, a);
                a = fmaf(xv[m].z, e.z, a);
                a = fmaf(xv[m].w, e.w, a);
                acc[m][kt] = a;
            }
        }
    }

    // per-row argmin over this k-group's 16 codes (kt ascending)
#pragma unroll
    for (int m = 0; m < RT; ++m) {
        float best = INFINITY; int bi = kbase + kg * KT;
#pragma unroll
        for (int kt = 0; kt < KT; ++kt) {
            // ref rounding: fl(fl(sx+se) - 2*acc); 2*acc exact
            float d = (sx[m] + se_s[kg * KT + kt]) - 2.0f * acc[m][kt];
            if (d < best) { best = d; bi = kbase + kg * KT + kt; }
        }
        part[kg][r + 64 * m] = make_float2(best, (float)bi);
    }
    __syncthreads();

    // wave 0 merges the 4 k-groups (kg ascending == k ascending)
    if (kg == 0) {
#pragma unroll
        for (int m = 0; m < RT; ++m) {
            const int rr = r + 64 * m;
            float best = INFINITY; int bi = 0;
#pragma unroll
            for (int g = 0; g < KG; ++g) {
                float2 p = part[g][rr];
                if (p.x < best) { best = p.x; bi = (int)p.y; }
            }
            const int row = rowbase + rr;
            if (row < N)
                *(float2*)(stash + (size_t)row * D + 2 * blockIdx.y) =
                    make_float2(best, (float)bi);
        }
    }
}

// Pass 2 (validated R5/R6 runs): 128 rows/block, 2 threads/row. Merge 8
// slice partials in slice order (== k order -> first occurrence), gather
// code, write q/idx, loss partials, histogram.
__global__ __launch_bounds__(BLOCK) void vq_merge(
    const float* __restrict__ x, const float* __restrict__ emb,
    float* __restrict__ q_out, float* __restrict__ idx_out,
    float* __restrict__ block_sums, int* __restrict__ counts, int N)
{
    __shared__ int hist[K];
    __shared__ int bi_s[128];
    __shared__ float red[BLOCK / 64];
    const int tid = threadIdx.x;
    const int r = tid & 127, h = tid >> 7;
    const int row = blockIdx.x * 128 + r;

    for (int k = tid; k < K; k += BLOCK) hist[k] = 0;
    __syncthreads();

    if (h == 0 && row < N) {
        const float* sp = q_out + (size_t)row * D;
        float4 s0 = *(const float4*)(sp + 0);
        float4 s1 = *(const float4*)(sp + 4);
        float4 s2 = *(const float4*)(sp + 8);
        float4 s3 = *(const float4*)(sp + 12);
        float best = INFINITY; int bi = 0;
        float dv[8] = { s0.x, s0.z, s1.x, s1.z, s2.x, s2.z, s3.x, s3.z };
        float kv[8] = { s0.y, s0.w, s1.y, s1.w, s2.y, s2.w, s3.y, s3.w };
#pragma unroll
        for (int sl = 0; sl < 8; ++sl)       // slice order == k order
            if (dv[sl] < best) { best = dv[sl]; bi = (int)kv[sl]; }
        bi_s[r] = bi;
        idx_out[row] = (float)bi;
        atomicAdd(&hist[bi], 1);
    }
    __syncthreads();

    float s = 0.f;
    if (row < N) {
        const int bi = bi_s[r];
        const float4* xp = (const float4*)(x + (size_t)row * D) + h * 8;
        const float4* ep = (const float4*)(emb + (size_t)bi * D) + h * 8;
        float4* qp = (float4*)(q_out + (size_t)row * D) + h * 8;
#pragma unroll
        for (int j = 0; j < 8; ++j) {
            float4 xv = xp[j];
            float4 e  = ep[j];
            float dx0 = e.x - xv.x, dx1 = e.y - xv.y;
            float dx2 = e.z - xv.z, dx3 = e.w - xv.w;
            s = fmaf(dx0, dx0, s);
            s = fmaf(dx1, dx1, s);
            s = fmaf(dx2, dx2, s);
            s = fmaf(dx3, dx3, s);
            float4 qs;  // straight-through: x + (q - x), ref rounding
            qs.x = xv.x + dx0; qs.y = xv.y + dx1;
            qs.z = xv.z + dx2; qs.w = xv.w + dx3;
            qp[j] = qs;
        }
    }

    for (int off = 32; off; off >>= 1) s += __shfl_down(s, off, 64);
    if ((tid & 63) == 0) red[tid >> 6] = s;
    __syncthreads();
    if (tid == 0) {
        float t = 0.f;
#pragma unroll
        for (int w = 0; w < BLOCK / 64; ++w) t += red[w];
        block_sums[blockIdx.x] = t;
    }
    for (int k = tid; k < K; k += BLOCK) {
        int hk = hist[k];
        if (hk) atomicAdd(&counts[k], hk);   // <=128 nonzero per block
    }
}

__global__ __launch_bounds__(512) void vq_finalize(
    const float* __restrict__ block_sums, int nblocks,
    const int* __restrict__ counts, float* __restrict__ out_loss,
    float* __restrict__ out_perp, float inv_nelem, float inv_rows)
{
    const int tid = threadIdx.x;
    double ls = 0.0;
    for (int i = tid; i < nblocks; i += 512) ls += (double)block_sums[i];
    double ps = 0.0;
    {
        float p = (float)counts[tid] * inv_rows;     // tid < 512 == K
        ps = (double)(p * logf(p + 1e-10f));
    }
    for (int off = 32; off; off >>= 1) {
        ls += __shfl_down(ls, off, 64);
        ps += __shfl_down(ps, off, 64);
    }
    __shared__ double l8[8], p8[8];
    if ((tid & 63) == 0) { l8[tid >> 6] = ls; p8[tid >> 6] = ps; }
    __syncthreads();
    if (tid == 0) {
        double L = 0.0, P = 0.0;
#pragma unroll
        for (int w = 0; w < 8; ++w) { L += l8[w]; P += p8[w]; }
        // loss = q_latent + 0.25*e_latent; forward values identical
        *out_loss = 1.25f * (float)(L * (double)inv_nelem);
        *out_perp = expf((float)(-P));
    }
}

extern "C" void kernel_launch(void* const* d_in, const int* in_sizes, int n_in,
                              void* d_out, int out_size, void* d_ws, size_t ws_size,
                              hipStream_t stream) {
    const float* x   = (const float*)d_in[0];
    const float* emb = (const float*)d_in[1];
    const int N = in_sizes[0] / D;                        // 65536 rows
    const int nScanRB = (N + ROWS_PB - 1) / ROWS_PB;      // 256
    const int nMergeB = (N + 127) / 128;                  // 512

    float* out      = (float*)d_out;
    float* loss_out = out;                  // [0]
    float* q_out    = out + 1;              // [1 .. N*D]
    float* perp_out = out + 1 + (size_t)N * D;
    float* idx_out  = perp_out + 1;         // [.. + N]

    float* block_sums = (float*)d_ws;
    int*   counts     = (int*)((char*)d_ws + (((size_t)nMergeB * 4 + 255) & ~(size_t)255));

    hipMemsetAsync(counts, 0, K * sizeof(int), stream);
    dim3 sgrid(nScanRB, NSLICES);
    vq_scan<<<sgrid, BLOCK, 0, stream>>>(x, emb, q_out, N);
    vq_merge<<<nMergeB, BLOCK, 0, stream>>>(x, emb, q_out, idx_out,
                                            block_sums, counts, N);
    vq_finalize<<<1, 512, 0, stream>>>(block_sums, nMergeB, counts,
                                       loss_out, perp_out,
                                       1.0f / (float)((size_t)N * D),
                                       1.0f / (float)N);
}

// Round 9
// 172.322 us; speedup vs baseline: 1.8084x; 1.8084x over previous
//
#include <hip/hip_runtime.h>
#include <math.h>

#define D 64
#define K 512
#define BLOCK 256
#define KSLICE 128              // K / NSLICES
#define NSLICES 4

// Bit-exact emulation of the harness's numpy fp32 reference (validated
// rounds 3-8 at absmax 0.0):
//   dist[i,k] = fp32( fp32(sx[i] + se[k]) - 2*dot[i,k] )   (2*dot exact)
// sx/se = numpy pairwise 8-accumulator sums of squares (contraction OFF),
// dot = single-accumulator fmaf chain, j = 0..63 strictly ascending.
// argmin strict-<, k ascending (slices ascending) -> first occurrence.
//
// R9 = R4's kernel (best scan so far: 93us, VALUBusy 72%, conflicts 0)
// with ONE change: amdgpu_waves_per_eu(2,2). R4's defect was the compiler
// choosing an 8-waves/EU target (VGPR cap 64) and spilling xr[64] to
// scratch (9.2MB scratch writes; VALU issue 67us = 2.5x the 27.3us FMA
// floor). Pinning 2 waves/EU gives a 256-VGPR budget -> xr stays in
// registers. 2 waves/SIMD saturates VALU issue (wave64 = 2cyc/instr) with
// the 2-chain ILP below; e-reads are wave-uniform LDS broadcasts (free).

// numpy pairwise sum of v[j]^2, n=64, streaming (validated R5-R8).
__device__ __forceinline__ float np_sumsq64_g(const float* v) {
#pragma clang fp contract(off)
    float r[8];
    {
        float4 a = *(const float4*)(v + 0);
        float4 b = *(const float4*)(v + 4);
        r[0] = a.x * a.x; r[1] = a.y * a.y; r[2] = a.z * a.z; r[3] = a.w * a.w;
        r[4] = b.x * b.x; r[5] = b.y * b.y; r[6] = b.z * b.z; r[7] = b.w * b.w;
    }
#pragma unroll
    for (int i = 1; i < 8; ++i) {
        float4 a = *(const float4*)(v + i * 8 + 0);
        float4 b = *(const float4*)(v + i * 8 + 4);
        r[0] = r[0] + a.x * a.x; r[1] = r[1] + a.y * a.y;
        r[2] = r[2] + a.z * a.z; r[3] = r[3] + a.w * a.w;
        r[4] = r[4] + b.x * b.x; r[5] = r[5] + b.y * b.y;
        r[6] = r[6] + b.z * b.z; r[7] = r[7] + b.w * b.w;
    }
    return ((r[0] + r[1]) + (r[2] + r[3])) + ((r[4] + r[5]) + (r[6] + r[7]));
}

// Pass 1: block = (256 rows) x (128-code slice). Stash (d, k) float2 per
// (row, slice) at q_out[row*64 + slice*2] (overwritten by merge later).
__global__ __launch_bounds__(BLOCK)
__attribute__((amdgpu_waves_per_eu(2, 2)))
void vq_scan(
    const float* __restrict__ x, const float* __restrict__ emb,
    float* __restrict__ stash, int N)
{
    __shared__ float4 e_s[KSLICE * (D / 4)];   // 32 KB
    __shared__ float se_s[KSLICE];

    const int tid = threadIdx.x;
    const int kbase = blockIdx.y * KSLICE;

    // stage slice (2048 float4s, coalesced, 8/thread)
    const float4* esrc = (const float4*)(emb + (size_t)kbase * D);
#pragma unroll
    for (int i = 0; i < (KSLICE * D / 4) / BLOCK; ++i)
        e_s[tid + i * BLOCK] = esrc[tid + i * BLOCK];
    if (tid < KSLICE)
        se_s[tid] = np_sumsq64_g(emb + (size_t)(kbase + tid) * D);
    __syncthreads();

    const int row = blockIdx.x * BLOCK + tid;
    if (row >= N) return;

    // row x in registers (budget 256 VGPR -> no spill)
    float xr[D];
    {
        const float4* xp = (const float4*)(x + (size_t)row * D);
#pragma unroll
        for (int j = 0; j < D / 4; ++j) {
            float4 v = xp[j];
            xr[4 * j + 0] = v.x; xr[4 * j + 1] = v.y;
            xr[4 * j + 2] = v.z; xr[4 * j + 3] = v.w;
        }
    }
    const float sx = np_sumsq64_g(x + (size_t)row * D);

    // two interleaved sequential fmaf chains (ILP=2); e reads wave-uniform
    float bestd = INFINITY;
    int bi = 0;
    for (int k = 0; k < KSLICE; k += 2) {
        float a0 = 0.f, a1 = 0.f;
        const float4* e0 = &e_s[k * (D / 4)];
        const float4* e1 = &e_s[(k + 1) * (D / 4)];
#pragma unroll
        for (int j = 0; j < D / 4; ++j) {
            float4 ea = e0[j];                 // broadcast ds_read_b128
            float4 eb = e1[j];
            // j-ascending sequential chain per (row,k) — exact ref order
            a0 = fmaf(xr[4 * j + 0], ea.x, a0);
            a1 = fmaf(xr[4 * j + 0], eb.x, a1);
            a0 = fmaf(xr[4 * j + 1], ea.y, a0);
            a1 = fmaf(xr[4 * j + 1], eb.y, a1);
            a0 = fmaf(xr[4 * j + 2], ea.z, a0);
            a1 = fmaf(xr[4 * j + 2], eb.z, a1);
            a0 = fmaf(xr[4 * j + 3], ea.w, a0);
            a1 = fmaf(xr[4 * j + 3], eb.w, a1);
        }
        float d0 = (sx + se_s[k]) - 2.0f * a0;      // ref rounding
        float d1 = (sx + se_s[k + 1]) - 2.0f * a1;
        if (d0 < bestd) { bestd = d0; bi = k; }     // k before k+1: first-min
        if (d1 < bestd) { bestd = d1; bi = k + 1; }
    }

    float2 p; p.x = bestd; p.y = (float)(kbase + bi);
    *(float2*)(stash + (size_t)row * D + 2 * blockIdx.y) = p;
}

// Pass 2: 128 rows/block, 2 threads/row. Merge 4 slice partials in slice
// order (== k order -> first occurrence), gather code, write q/idx, loss
// partials, histogram. (Validated R4/R5 structure.)
__global__ __launch_bounds__(BLOCK) void vq_merge(
    const float* __restrict__ x, const float* __restrict__ emb,
    float* __restrict__ q_out, float* __restrict__ idx_out,
    float* __restrict__ block_sums, int* __restrict__ counts, int N)
{
    __shared__ int hist[K];
    __shared__ int bi_s[128];
    __shared__ float red[BLOCK / 64];
    const int tid = threadIdx.x;
    const int r = tid & 127, h = tid >> 7;
    const int row = blockIdx.x * 128 + r;

    for (int k = tid; k < K; k += BLOCK) hist[k] = 0;
    __syncthreads();

    if (h == 0 && row < N) {
        const float* sp = q_out + (size_t)row * D;
        float4 s0 = *(const float4*)(sp + 0);
        float4 s1 = *(const float4*)(sp + 4);
        float best = INFINITY; int bi = 0;
        float dv[4] = { s0.x, s0.z, s1.x, s1.z };
        float kv[4] = { s0.y, s0.w, s1.y, s1.w };
#pragma unroll
        for (int sl = 0; sl < NSLICES; ++sl)   // slice order == k order
            if (dv[sl] < best) { best = dv[sl]; bi = (int)kv[sl]; }
        bi_s[r] = bi;
        idx_out[row] = (float)bi;
        atomicAdd(&hist[bi], 1);
    }
    __syncthreads();

    float s = 0.f;
    if (row < N) {
        const int bi = bi_s[r];
        const float4* xp = (const float4*)(x + (size_t)row * D) + h * 8;
        const float4* ep = (const float4*)(emb + (size_t)bi * D) + h * 8;
        float4* qp = (float4*)(q_out + (size_t)row * D) + h * 8;
#pragma unroll
        for (int j = 0; j < 8; ++j) {
            float4 xv = xp[j];
            float4 e  = ep[j];
            float dx0 = e.x - xv.x, dx1 = e.y - xv.y;
            float dx2 = e.z - xv.z, dx3 = e.w - xv.w;
            s = fmaf(dx0, dx0, s);
            s = fmaf(dx1, dx1, s);
            s = fmaf(dx2, dx2, s);
            s = fmaf(dx3, dx3, s);
            float4 qs;  // straight-through: x + (q - x), ref rounding
            qs.x = xv.x + dx0; qs.y = xv.y + dx1;
            qs.z = xv.z + dx2; qs.w = xv.w + dx3;
            qp[j] = qs;
        }
    }

    for (int off = 32; off; off >>= 1) s += __shfl_down(s, off, 64);
    if ((tid & 63) == 0) red[tid >> 6] = s;
    __syncthreads();
    if (tid == 0) {
        float t = 0.f;
#pragma unroll
        for (int w = 0; w < BLOCK / 64; ++w) t += red[w];
        block_sums[blockIdx.x] = t;
    }
    for (int k = tid; k < K; k += BLOCK) {
        int hk = hist[k];
        if (hk) atomicAdd(&counts[k], hk);   // <=128 nonzero per block
    }
}

__global__ __launch_bounds__(512) void vq_finalize(
    const float* __restrict__ block_sums, int nblocks,
    const int* __restrict__ counts, float* __restrict__ out_loss,
    float* __restrict__ out_perp, float inv_nelem, float inv_rows)
{
    const int tid = threadIdx.x;
    double ls = 0.0;
    for (int i = tid; i < nblocks; i += 512) ls += (double)block_sums[i];
    double ps = 0.0;
    {
        float p = (float)counts[tid] * inv_rows;     // tid < 512 == K
        ps = (double)(p * logf(p + 1e-10f));
    }
    for (int off = 32; off; off >>= 1) {
        ls += __shfl_down(ls, off, 64);
        ps += __shfl_down(ps, off, 64);
    }
    __shared__ double l8[8], p8[8];
    if ((tid & 63) == 0) { l8[tid >> 6] = ls; p8[tid >> 6] = ps; }
    __syncthreads();
    if (tid == 0) {
        double L = 0.0, P = 0.0;
#pragma unroll
        for (int w = 0; w < 8; ++w) { L += l8[w]; P += p8[w]; }
        // loss = q_latent + 0.25*e_latent; forward values identical
        *out_loss = 1.25f * (float)(L * (double)inv_nelem);
        *out_perp = expf((float)(-P));
    }
}

extern "C" void kernel_launch(void* const* d_in, const int* in_sizes, int n_in,
                              void* d_out, int out_size, void* d_ws, size_t ws_size,
                              hipStream_t stream) {
    const float* x   = (const float*)d_in[0];
    const float* emb = (const float*)d_in[1];
    const int N = in_sizes[0] / D;          // 65536 rows
    const int nScanRB = (N + BLOCK - 1) / BLOCK;   // 256
    const int nMergeB = (N + 127) / 128;           // 512

    float* out      = (float*)d_out;
    float* loss_out = out;                  // [0]
    float* q_out    = out + 1;              // [1 .. N*D]
    float* perp_out = out + 1 + (size_t)N * D;
    float* idx_out  = perp_out + 1;         // [.. + N]

    float* block_sums = (float*)d_ws;
    int*   counts     = (int*)((char*)d_ws + (((size_t)nMergeB * 4 + 255) & ~(size_t)255));

    hipMemsetAsync(counts, 0, K * sizeof(int), stream);
    dim3 sgrid(nScanRB, NSLICES);
    vq_scan<<<sgrid, BLOCK, 0, stream>>>(x, emb, q_out, N);
    vq_merge<<<nMergeB, BLOCK, 0, stream>>>(x, emb, q_out, idx_out,
                                            block_sums, counts, N);
    vq_finalize<<<1, 512, 0, stream>>>(block_sums, nMergeB, counts,
                                       loss_out, perp_out,
                                       1.0f / (float)((size_t)N * D),
                                       1.0f / (float)N);
}